// Round 1
// baseline (488.191 us; speedup 1.0000x reference)
//
#include <hip/hip_runtime.h>
#include <hip/hip_bf16.h>

// FastCapsNetMulti: conv(144->32, 3x3) + conv(4->32, 3x3) -> squash(8-dim caps)
// -> s[b,c,j] = sum_{n,d} caps[b,n,d]*W[n,c,j,d]/8192 -> squash -> |v|
// B=64, H=W=32, N=8192, classes=10, class_dim=16, cap_dim=8.

#define B_SZ 64
#define HW 32
#define NCAPS_N 8192   // total n
#define NCJ 160        // 10*16
#define ROUTE_NCHUNK 16
#define ROUTE_BLOCKS (NCAPS_N / ROUTE_NCHUNK)   // 512

// ---------------- weight transpose: w[oc][cin][ky][kx] -> wt[cin][tap][oc] ----
__global__ void transpose_w_kernel(const float* __restrict__ w, float* __restrict__ wt,
                                   int cin_total) {
    int idx = blockIdx.x * blockDim.x + threadIdx.x;
    int total = 32 * cin_total * 9;
    if (idx >= total) return;
    int oc = idx & 31;
    int rest = idx >> 5;        // cin*9 + tap
    int tap = rest % 9;
    int cin = rest / 9;
    wt[idx] = w[(oc * cin_total + cin) * 9 + tap];
}

// ---------------- conv + bias + squash -> caps_t[n][b][8] ---------------------
// grid: B * 16 blocks (2 rows y per block), 256 threads:
//   x = t&31, cap = (t>>5)&3, yy = t>>7
template <int CIN>
__global__ __launch_bounds__(256) void conv_caps_kernel(
        const float* __restrict__ xin, const float* __restrict__ wt,
        const float* __restrict__ bias, float* __restrict__ caps_t, int n_base) {
    int t = threadIdx.x;
    int x = t & 31;
    int cap = (t >> 5) & 3;
    int yy = t >> 7;
    int bidx = blockIdx.x;
    int y = ((bidx & 15) << 1) + yy;
    int b = bidx >> 4;

    const float* xb = xin + (size_t)b * CIN * HW * HW;

    float acc[8];
    #pragma unroll
    for (int d = 0; d < 8; ++d) acc[d] = bias[cap * 8 + d];

    #pragma unroll
    for (int ky = 0; ky < 3; ++ky) {
        int iy = y + ky - 1;
        if (iy < 0 || iy >= HW) continue;   // wave-uniform branch
        for (int cin = 0; cin < CIN; ++cin) {
            const float* xrow = xb + (size_t)(cin * HW + iy) * HW;
            const float* wrow = wt + (size_t)(cin * 9 + ky * 3) * 32 + cap * 8;
            #pragma unroll
            for (int kx = 0; kx < 3; ++kx) {
                int ix = x + kx - 1;
                float v = (ix >= 0 && ix < HW) ? xrow[ix] : 0.0f;
                const float4 w0 = *reinterpret_cast<const float4*>(wrow + kx * 32);
                const float4 w1 = *reinterpret_cast<const float4*>(wrow + kx * 32 + 4);
                acc[0] += v * w0.x; acc[1] += v * w0.y;
                acc[2] += v * w0.z; acc[3] += v * w0.w;
                acc[4] += v * w1.x; acc[5] += v * w1.y;
                acc[6] += v * w1.z; acc[7] += v * w1.w;
            }
        }
    }

    // squash over the 8-dim capsule
    float sq = 0.0f;
    #pragma unroll
    for (int d = 0; d < 8; ++d) sq += acc[d] * acc[d];
    float scale = sq / ((1.0f + sq) * sqrtf(sq + 1e-8f));

    int pix = y * HW + x;
    int n = n_base + pix * 4 + cap;
    float* dst = caps_t + ((size_t)n * B_SZ + b) * 8;
    float4 o0 = make_float4(acc[0] * scale, acc[1] * scale, acc[2] * scale, acc[3] * scale);
    float4 o1 = make_float4(acc[4] * scale, acc[5] * scale, acc[6] * scale, acc[7] * scale);
    *reinterpret_cast<float4*>(dst) = o0;
    *reinterpret_cast<float4*>(dst + 4) = o1;
}

// ---------------- routing partial sums ---------------------------------------
// grid: 512 blocks (16 n each), 256 threads: lane b = t&63, wave cg = t>>6
// each thread accumulates 40 (c,j) pairs for its b over the n-chunk.
__global__ __launch_bounds__(256) void routing_partial_kernel(
        const float* __restrict__ caps_t, const float* __restrict__ W,
        float* __restrict__ partials) {
    int t = threadIdx.x;
    int b = t & 63;
    int cg = t >> 6;           // 0..3 -> cj range [cg*40, cg*40+40)
    int n0 = blockIdx.x * ROUTE_NCHUNK;

    float acc[40];
    #pragma unroll
    for (int i = 0; i < 40; ++i) acc[i] = 0.0f;

    for (int n = n0; n < n0 + ROUTE_NCHUNK; ++n) {
        const float* cp = caps_t + ((size_t)n * B_SZ + b) * 8;
        float4 c0 = *reinterpret_cast<const float4*>(cp);
        float4 c1 = *reinterpret_cast<const float4*>(cp + 4);
        const float* Wn = W + (size_t)n * NCJ * 8 + (size_t)cg * 40 * 8;
        #pragma unroll
        for (int i = 0; i < 40; ++i) {
            float4 w0 = *reinterpret_cast<const float4*>(Wn + i * 8);
            float4 w1 = *reinterpret_cast<const float4*>(Wn + i * 8 + 4);
            acc[i] += c0.x * w0.x + c0.y * w0.y + c0.z * w0.z + c0.w * w0.w
                    + c1.x * w1.x + c1.y * w1.y + c1.z * w1.z + c1.w * w1.w;
        }
    }

    float* out = partials + ((size_t)blockIdx.x * B_SZ + b) * NCJ + cg * 40;
    #pragma unroll
    for (int i = 0; i < 40; ++i) out[i] = acc[i];
}

// ---------------- final reduce + squash + norm -------------------------------
// grid: 64 blocks (one per b), 256 threads.
__global__ __launch_bounds__(256) void finalize_kernel(
        const float* __restrict__ partials, float* __restrict__ out) {
    __shared__ float s_sh[NCJ];
    int t = threadIdx.x;
    int b = blockIdx.x;
    if (t < NCJ) {
        float s = 0.0f;
        #pragma unroll 8
        for (int p = 0; p < ROUTE_BLOCKS; ++p)
            s += partials[((size_t)p * B_SZ + b) * NCJ + t];
        s_sh[t] = s * (1.0f / 8192.0f);
    }
    __syncthreads();
    if (t < 10) {
        float sq = 0.0f;
        #pragma unroll
        for (int j = 0; j < 16; ++j) {
            float v = s_sh[t * 16 + j];
            sq += v * v;
        }
        float scale = sq / ((1.0f + sq) * sqrtf(sq + 1e-8f));
        out[b * 10 + t] = sqrtf(sq) * scale;
    }
}

extern "C" void kernel_launch(void* const* d_in, const int* in_sizes, int n_in,
                              void* d_out, int out_size, void* d_ws, size_t ws_size,
                              hipStream_t stream) {
    const float* x_hsi = (const float*)d_in[0];   // [64,144,32,32]
    const float* x_sar = (const float*)d_in[1];   // [64,4,32,32]
    const float* wh    = (const float*)d_in[2];   // [32,144,3,3]
    const float* bh    = (const float*)d_in[3];   // [32]
    const float* wsar  = (const float*)d_in[4];   // [32,4,3,3]
    const float* bs    = (const float*)d_in[5];   // [32]
    const float* W     = (const float*)d_in[6];   // [8192,10,16,8]
    float* out = (float*)d_out;                   // [64,10]

    char* ws = (char*)d_ws;
    // layout (bytes):
    //   wt_h:     [0,            165888)
    //   wt_s:     [166912,       171520)
    //   caps_t:   [172032,       172032 + 16777216)       = [n][b][8] f32
    //   partials: [16949248,     16949248 + 20971520)     = [512][64][160] f32
    float* wt_h     = (float*)(ws + 0);
    float* wt_s     = (float*)(ws + 166912);
    float* caps_t   = (float*)(ws + 172032);
    float* partials = (float*)(ws + 16949248);

    transpose_w_kernel<<<162, 256, 0, stream>>>(wh, wt_h, 144);
    transpose_w_kernel<<<5, 256, 0, stream>>>(wsar, wt_s, 4);

    conv_caps_kernel<144><<<dim3(B_SZ * 16), dim3(256), 0, stream>>>(
        x_hsi, wt_h, bh, caps_t, 0);
    conv_caps_kernel<4><<<dim3(B_SZ * 16), dim3(256), 0, stream>>>(
        x_sar, wt_s, bs, caps_t, 4096);

    routing_partial_kernel<<<dim3(ROUTE_BLOCKS), dim3(256), 0, stream>>>(
        caps_t, W, partials);

    finalize_kernel<<<dim3(B_SZ), dim3(256), 0, stream>>>(partials, out);
}

// Round 2
// 312.665 us; speedup vs baseline: 1.5614x; 1.5614x over previous
//
#include <hip/hip_runtime.h>
#include <hip/hip_bf16.h>

// FastCapsNetMulti: conv(144->32, 3x3) + conv(4->32, 3x3) -> squash(8-dim caps)
// -> s[b,c,j] = sum_{n,d} caps[b,n,d]*W[n,c,j,d]/8192 -> squash -> |v|
// B=64, H=W=32, N=8192, classes=10, class_dim=16, cap_dim=8.

#define B_SZ 64
#define HW 32
#define NCAPS_N 8192
#define NCJ 160
#define ROUTE_NCHUNK 16
#define ROUTE_BLOCKS (NCAPS_N / ROUTE_NCHUNK)   // 512

// ---------------- weight transpose: w[oc][cin][ky][kx] -> wt[cin][tap][oc] ----
__global__ void transpose_w_kernel(const float* __restrict__ w, float* __restrict__ wt,
                                   int cin_total) {
    int idx = blockIdx.x * blockDim.x + threadIdx.x;
    int total = 32 * cin_total * 9;
    if (idx >= total) return;
    int oc = idx & 31;
    int rest = idx >> 5;        // cin*9 + tap
    int tap = rest % 9;
    int cin = rest / 9;
    wt[idx] = w[(oc * cin_total + cin) * 9 + tap];
}

// ---------------- conv + bias + squash -> caps_t[n][b][8] ---------------------
// Block: 256 threads = 4 waves. Wave w handles cin subset [w*CIN/4, (w+1)*CIN/4)
// for the SAME 64 pixels (2 rows x 32 cols); cross-wave reduce via LDS.
// Each thread: 1 pixel, acc[32] (all output channels) -> 96 independent FMAs
// per 3 input loads; weight addresses wave-uniform -> scalar loads.
// grid: B * 16 (row-pairs)
template <int CIN>
__global__ __launch_bounds__(256) void conv_caps_kernel(
        const float* __restrict__ xin, const float* __restrict__ wt,
        const float* __restrict__ bias, float* __restrict__ caps_t, int n_base) {
    constexpr int CPW = CIN / 4;
    __shared__ float red[4][32][64];   // [wave][oc][lane] = 32 KB

    int t = threadIdx.x;
    int wave = __builtin_amdgcn_readfirstlane(t >> 6);
    int lane = t & 63;
    int x = lane & 31;
    int yy = lane >> 5;
    int bidx = blockIdx.x;
    int b = bidx >> 4;
    int y = ((bidx & 15) << 1) + yy;

    const float* xb = xin + (size_t)b * CIN * (HW * HW);

    float acc[32];
    #pragma unroll
    for (int oc = 0; oc < 32; ++oc) acc[oc] = 0.0f;

    for (int ci = 0; ci < CPW; ++ci) {
        int cin = wave * CPW + ci;          // wave-uniform
        const float* xc = xb + (size_t)cin * (HW * HW);
        const float* wc = wt + (size_t)cin * 288;   // [9][32]
        #pragma unroll
        for (int ky = 0; ky < 3; ++ky) {
            int iy = y + ky - 1;
            bool rowok = (iy >= 0) && (iy < HW);
            const float* xrow = xc + iy * HW;
            float v0 = (rowok && x > 0)      ? xrow[x - 1] : 0.0f;
            float v1 = rowok                 ? xrow[x]     : 0.0f;
            float v2 = (rowok && x < HW - 1) ? xrow[x + 1] : 0.0f;
            const float* wk = wc + ky * 96;  // [kx][32], wave-uniform address
            #pragma unroll
            for (int oc = 0; oc < 32; ++oc) {
                acc[oc] += v0 * wk[oc] + v1 * wk[32 + oc] + v2 * wk[64 + oc];
            }
        }
    }

    // cross-wave reduction through LDS: red[wave][oc][lane]
    #pragma unroll
    for (int oc = 0; oc < 32; ++oc) red[wave][oc][lane] = acc[oc];
    __syncthreads();

    // epilogue: thread = (cap, pixel): cap = t>>6, p = t&63
    int cap = t >> 6;
    int p = t & 63;
    float s[8];
    #pragma unroll
    for (int d = 0; d < 8; ++d) {
        int oc = cap * 8 + d;
        s[d] = bias[oc] + red[0][oc][p] + red[1][oc][p] + red[2][oc][p] + red[3][oc][p];
    }
    float sq = 0.0f;
    #pragma unroll
    for (int d = 0; d < 8; ++d) sq += s[d] * s[d];
    float scale = sq / ((1.0f + sq) * sqrtf(sq + 1e-8f));

    int pix = (((bidx & 15) << 1) + (p >> 5)) * HW + (p & 31);
    int n = n_base + pix * 4 + cap;
    float* dst = caps_t + ((size_t)n * B_SZ + b) * 8;
    *reinterpret_cast<float4*>(dst) =
        make_float4(s[0] * scale, s[1] * scale, s[2] * scale, s[3] * scale);
    *reinterpret_cast<float4*>(dst + 4) =
        make_float4(s[4] * scale, s[5] * scale, s[6] * scale, s[7] * scale);
}

// ---------------- routing partial sums ---------------------------------------
// grid: 512 blocks (16 n each), 256 threads: lane b = t&63, wave cg = t>>6
// cg forced wave-uniform -> W loads become scalar (s_load), 320 FMA per n
// per thread against 2 float4 vector loads.
__global__ __launch_bounds__(256) void routing_partial_kernel(
        const float* __restrict__ caps_t, const float* __restrict__ W,
        float* __restrict__ partials) {
    int t = threadIdx.x;
    int b = t & 63;
    int cg = __builtin_amdgcn_readfirstlane(t >> 6);   // 0..3 -> cj [cg*40, cg*40+40)
    int n0 = blockIdx.x * ROUTE_NCHUNK;

    float acc[40];
    #pragma unroll
    for (int i = 0; i < 40; ++i) acc[i] = 0.0f;

    for (int n = n0; n < n0 + ROUTE_NCHUNK; ++n) {
        const float* cp = caps_t + ((size_t)n * B_SZ + b) * 8;
        float4 c0 = *reinterpret_cast<const float4*>(cp);
        float4 c1 = *reinterpret_cast<const float4*>(cp + 4);
        const float* Wn = W + (size_t)n * NCJ * 8 + (size_t)cg * 40 * 8;  // uniform
        #pragma unroll
        for (int i = 0; i < 40; ++i) {
            float w0 = Wn[i * 8 + 0], w1 = Wn[i * 8 + 1], w2 = Wn[i * 8 + 2], w3 = Wn[i * 8 + 3];
            float w4 = Wn[i * 8 + 4], w5 = Wn[i * 8 + 5], w6 = Wn[i * 8 + 6], w7 = Wn[i * 8 + 7];
            acc[i] += c0.x * w0 + c0.y * w1 + c0.z * w2 + c0.w * w3
                    + c1.x * w4 + c1.y * w5 + c1.z * w6 + c1.w * w7;
        }
    }

    float* out = partials + ((size_t)blockIdx.x * B_SZ + b) * NCJ + cg * 40;
    #pragma unroll
    for (int i = 0; i < 40; ++i) out[i] = acc[i];
}

// ---------------- final reduce + squash + norm -------------------------------
// grid: 64 blocks (one per b), 256 threads.
__global__ __launch_bounds__(256) void finalize_kernel(
        const float* __restrict__ partials, float* __restrict__ out) {
    __shared__ float s_sh[NCJ];
    int t = threadIdx.x;
    int b = blockIdx.x;
    if (t < NCJ) {
        float s = 0.0f;
        #pragma unroll 8
        for (int p = 0; p < ROUTE_BLOCKS; ++p)
            s += partials[((size_t)p * B_SZ + b) * NCJ + t];
        s_sh[t] = s * (1.0f / 8192.0f);
    }
    __syncthreads();
    if (t < 10) {
        float sq = 0.0f;
        #pragma unroll
        for (int j = 0; j < 16; ++j) {
            float v = s_sh[t * 16 + j];
            sq += v * v;
        }
        float scale = sq / ((1.0f + sq) * sqrtf(sq + 1e-8f));
        out[b * 10 + t] = sqrtf(sq) * scale;
    }
}

extern "C" void kernel_launch(void* const* d_in, const int* in_sizes, int n_in,
                              void* d_out, int out_size, void* d_ws, size_t ws_size,
                              hipStream_t stream) {
    const float* x_hsi = (const float*)d_in[0];   // [64,144,32,32]
    const float* x_sar = (const float*)d_in[1];   // [64,4,32,32]
    const float* wh    = (const float*)d_in[2];   // [32,144,3,3]
    const float* bh    = (const float*)d_in[3];   // [32]
    const float* wsar  = (const float*)d_in[4];   // [32,4,3,3]
    const float* bs    = (const float*)d_in[5];   // [32]
    const float* W     = (const float*)d_in[6];   // [8192,10,16,8]
    float* out = (float*)d_out;                   // [64,10]

    char* ws = (char*)d_ws;
    float* wt_h     = (float*)(ws + 0);           // 144*9*32 f32 = 165888 B
    float* wt_s     = (float*)(ws + 166912);      // 4*9*32 f32
    float* caps_t   = (float*)(ws + 172032);      // [8192][64][8] f32 = 16 MB
    float* partials = (float*)(ws + 16949248);    // [512][64][160] f32 = 21 MB

    transpose_w_kernel<<<162, 256, 0, stream>>>(wh, wt_h, 144);
    transpose_w_kernel<<<5, 256, 0, stream>>>(wsar, wt_s, 4);

    conv_caps_kernel<144><<<dim3(B_SZ * 16), dim3(256), 0, stream>>>(
        x_hsi, wt_h, bh, caps_t, 0);
    conv_caps_kernel<4><<<dim3(B_SZ * 16), dim3(256), 0, stream>>>(
        x_sar, wt_s, bs, caps_t, 4096);

    routing_partial_kernel<<<dim3(ROUTE_BLOCKS), dim3(256), 0, stream>>>(
        caps_t, W, partials);

    finalize_kernel<<<dim3(B_SZ), dim3(256), 0, stream>>>(partials, out);
}

// Round 3
// 84.157 us; speedup vs baseline: 5.8009x; 3.7152x over previous
//
#include <hip/hip_runtime.h>
#include <hip/hip_bf16.h>

// FastCapsNetMulti via bf16 MFMA:
//  conv(144->32,3x3) as 9 shifted GEMMs (16x16x32 MFMA) + bias + squash
//  conv(4->32,3x3) in fp32 VALU (tiny)
//  routing s[b,cj] = sum_{n,d} caps*W as M64 x N160 x K65536 MFMA GEMM
//  finalize: reduce + squash + |v|
// B=64, H=W=32, N=8192, classes=10, class_dim=16, cap_dim=8.

#define B_SZ 64
#define HW 32

typedef __attribute__((ext_vector_type(8))) short bf16x8s;
typedef __attribute__((ext_vector_type(4))) float f32x4;

__device__ inline short f2bf(float f) {
    __hip_bfloat16 h = __float2bfloat16(f);
    return *reinterpret_cast<short*>(&h);
}

// ---------------- prep: wh[32][144][9] -> wtb[9][32][160] bf16 (zero-pad cin) --
__global__ __launch_bounds__(256) void prep_w_kernel(const float* __restrict__ wh,
                                                     short* __restrict__ wtb) {
    int idx = blockIdx.x * 256 + threadIdx.x;   // < 9*32*160 = 46080
    int tap = idx / 5120;
    int rest = idx - tap * 5120;
    int oc = rest / 160;
    int cin = rest - oc * 160;
    short v = 0;
    if (cin < 144) v = f2bf(wh[(oc * 144 + cin) * 9 + tap]);
    wtb[idx] = v;
}

// ---------------- prep: x[b][cin][y][x] f32 -> xb[b][y][x][160] bf16 ----------
// grid: 64*32 blocks (b,y), 256 threads. LDS tile [cin][33 x] to avoid conflicts.
__global__ __launch_bounds__(256) void prep_x_kernel(const float* __restrict__ xin,
                                                     short* __restrict__ xb) {
    __shared__ short tile[160 * 33];
    int t = threadIdx.x;
    int b = blockIdx.x >> 5;
    int y = blockIdx.x & 31;
    // zero cin 144..159
    for (int idx = t; idx < 512; idx += 256) {
        int x = idx & 31, cin = 144 + (idx >> 5);
        tile[cin * 33 + x] = 0;
    }
    for (int base = 0; base < 144; base += 8) {
        int cin = base + (t >> 5), x = t & 31;
        float v = xin[(((size_t)b * 144 + cin) * 32 + y) * 32 + x];
        tile[cin * 33 + x] = f2bf(v);
    }
    __syncthreads();
    // write out [x][cin] contiguous as u32 pairs
    unsigned* dst = (unsigned*)(xb + ((size_t)(b * 32 + y) * 32) * 160);
    for (int idx = t; idx < 2560; idx += 256) {
        int x = idx / 80;
        int cinp = idx - x * 80;          // cin pair
        unsigned lo = (unsigned short)tile[(2 * cinp) * 33 + x];
        unsigned hi = (unsigned short)tile[(2 * cinp + 1) * 33 + x];
        dst[idx] = lo | (hi << 16);
    }
}

// ---------------- SAR weight transpose (fp32): w[oc][cin][tap] -> wt[cin][tap][oc]
__global__ void transpose_w_kernel(const float* __restrict__ w, float* __restrict__ wt,
                                   int cin_total) {
    int idx = blockIdx.x * blockDim.x + threadIdx.x;
    int total = 32 * cin_total * 9;
    if (idx >= total) return;
    int oc = idx & 31;
    int rest = idx >> 5;
    int tap = rest % 9;
    int cin = rest / 9;
    wt[idx] = w[(oc * cin_total + cin) * 9 + tap];
}

// ---------------- HSI conv via MFMA ------------------------------------------
// grid: b(64) x ypair(16) = 1024 blocks, 4 waves = (mhalf row) x (oc n-tile).
// wave: C-tile = 32 px (one row) x 16 oc, K = 9 taps x 160 cin.
__global__ __launch_bounds__(256) void conv_mfma_kernel(
        const short* __restrict__ xb, const short* __restrict__ wtb,
        const float* __restrict__ bias, short* __restrict__ capsb) {
    __shared__ float ctile[64][34];
    int t = threadIdx.x;
    int l = t & 63;
    int wv = t >> 6;
    int mhalf = wv >> 1;
    int nt = wv & 1;
    int l15 = l & 15, lhi = l >> 4;
    int b = blockIdx.x >> 4;
    int y0 = (blockIdx.x & 15) << 1;
    int y = y0 + mhalf;
    int kofs = lhi * 8;

    const short* xbb = xb + (size_t)b * 1024 * 160;

    f32x4 acc0 = {0.f, 0.f, 0.f, 0.f};
    f32x4 acc1 = {0.f, 0.f, 0.f, 0.f};
    const bf16x8s zfrag = {0, 0, 0, 0, 0, 0, 0, 0};

    #pragma unroll
    for (int tap = 0; tap < 9; ++tap) {
        int dy = tap / 3, dx = tap % 3;
        int iy = y + dy - 1;
        bool rowok = (unsigned)iy < 32u;
        int iyc = rowok ? iy : 0;
        int ix0 = l15 + dx - 1;
        int ix1 = 16 + l15 + dx - 1;
        bool ok0 = rowok && ((unsigned)ix0 < 32u);
        bool ok1 = rowok && ((unsigned)ix1 < 32u);
        int ix0c = min(max(ix0, 0), 31);
        int ix1c = min(max(ix1, 0), 31);
        const short* xa0 = xbb + ((size_t)(iyc * 32 + ix0c)) * 160 + kofs;
        const short* xa1 = xbb + ((size_t)(iyc * 32 + ix1c)) * 160 + kofs;
        const short* wa = wtb + ((size_t)tap * 32 + nt * 16 + l15) * 160 + kofs;
        #pragma unroll
        for (int kc = 0; kc < 5; ++kc) {
            bf16x8s bfrag = *(const bf16x8s*)(wa + kc * 32);
            bf16x8s a0 = *(const bf16x8s*)(xa0 + kc * 32);
            bf16x8s a1 = *(const bf16x8s*)(xa1 + kc * 32);
            a0 = ok0 ? a0 : zfrag;
            a1 = ok1 ? a1 : zfrag;
            acc0 = __builtin_amdgcn_mfma_f32_16x16x32_bf16(a0, bfrag, acc0, 0, 0, 0);
            acc1 = __builtin_amdgcn_mfma_f32_16x16x32_bf16(a1, bfrag, acc1, 0, 0, 0);
        }
    }

    // C[row=(lhi*4+r) within m-tile][col=l15] -> ctile[pixel][oc]
    #pragma unroll
    for (int r = 0; r < 4; ++r) {
        ctile[mhalf * 32 + lhi * 4 + r][nt * 16 + l15] = acc0[r];
        ctile[mhalf * 32 + 16 + lhi * 4 + r][nt * 16 + l15] = acc1[r];
    }
    __syncthreads();

    // epilogue: t -> capsule (p = t>>2 in 0..63, cap = t&3)
    int p = t >> 2;
    int cap = t & 3;
    float s[8];
    float sq = 0.0f;
    #pragma unroll
    for (int d = 0; d < 8; ++d) {
        s[d] = ctile[p][cap * 8 + d] + bias[cap * 8 + d];
        sq += s[d] * s[d];
    }
    float scale = sq / ((1.0f + sq) * sqrtf(sq + 1e-8f));
    int pix = (y0 + (p >> 5)) * 32 + (p & 31);
    int n = pix * 4 + cap;
    bf16x8s o;
    #pragma unroll
    for (int d = 0; d < 8; ++d) o[d] = f2bf(s[d] * scale);
    *(bf16x8s*)(capsb + ((size_t)b * 8192 + n) * 8) = o;
}

// ---------------- SAR conv (fp32 VALU, CIN=4) -> bf16 caps -------------------
__global__ __launch_bounds__(256) void conv_caps_sar_kernel(
        const float* __restrict__ xin, const float* __restrict__ wt,
        const float* __restrict__ bias, short* __restrict__ capsb, int n_base) {
    constexpr int CIN = 4;
    __shared__ float red[4][32][64];
    int t = threadIdx.x;
    int wave = __builtin_amdgcn_readfirstlane(t >> 6);
    int lane = t & 63;
    int x = lane & 31;
    int yy = lane >> 5;
    int bidx = blockIdx.x;
    int b = bidx >> 4;
    int y = ((bidx & 15) << 1) + yy;

    const float* xb_ = xin + (size_t)b * CIN * (HW * HW);

    float acc[32];
    #pragma unroll
    for (int oc = 0; oc < 32; ++oc) acc[oc] = 0.0f;

    {
        int cin = wave;   // CIN==4, one per wave
        const float* xc = xb_ + (size_t)cin * (HW * HW);
        const float* wc = wt + (size_t)cin * 288;
        #pragma unroll
        for (int ky = 0; ky < 3; ++ky) {
            int iy = y + ky - 1;
            bool rowok = (iy >= 0) && (iy < HW);
            const float* xrow = xc + iy * HW;
            float v0 = (rowok && x > 0)      ? xrow[x - 1] : 0.0f;
            float v1 = rowok                 ? xrow[x]     : 0.0f;
            float v2 = (rowok && x < HW - 1) ? xrow[x + 1] : 0.0f;
            const float* wk = wc + ky * 96;
            #pragma unroll
            for (int oc = 0; oc < 32; ++oc) {
                acc[oc] += v0 * wk[oc] + v1 * wk[32 + oc] + v2 * wk[64 + oc];
            }
        }
    }

    #pragma unroll
    for (int oc = 0; oc < 32; ++oc) red[wave][oc][lane] = acc[oc];
    __syncthreads();

    int cap = t >> 6;
    int p = t & 63;
    float s[8];
    float sq = 0.0f;
    #pragma unroll
    for (int d = 0; d < 8; ++d) {
        int oc = cap * 8 + d;
        s[d] = bias[oc] + red[0][oc][p] + red[1][oc][p] + red[2][oc][p] + red[3][oc][p];
        sq += s[d] * s[d];
    }
    float scale = sq / ((1.0f + sq) * sqrtf(sq + 1e-8f));
    int pix = (((bidx & 15) << 1) + (p >> 5)) * HW + (p & 31);
    int n = n_base + pix * 4 + cap;
    bf16x8s o;
    #pragma unroll
    for (int d = 0; d < 8; ++d) o[d] = f2bf(s[d] * scale);
    *(bf16x8s*)(capsb + ((size_t)b * 8192 + n) * 8) = o;
}

// ---------------- routing via MFMA -------------------------------------------
// grid: (kc 64) x (ntile 10), 256 thr = 4 waves, wave = 8 k-steps (32 n each chunk).
// A[b][k=n*8+d] = capsb; B[k][cj] = W[n][cj][d] loaded fp32 -> bf16 inline.
__global__ __launch_bounds__(256) void routing_mfma_kernel(
        const short* __restrict__ capsb, const float* __restrict__ W,
        float* __restrict__ partials) {
    __shared__ float red[4][64][18];
    int t = threadIdx.x;
    int l = t & 63;
    int wv = t >> 6;
    int l15 = l & 15, lhi = l >> 4;
    int kc = blockIdx.x;
    int ntile = blockIdx.y;
    int cj = ntile * 16 + l15;

    f32x4 acc[4] = {{0.f,0.f,0.f,0.f},{0.f,0.f,0.f,0.f},{0.f,0.f,0.f,0.f},{0.f,0.f,0.f,0.f}};

    int kk0 = kc * 32 + wv * 8;
    for (int ks = 0; ks < 8; ++ks) {
        int n = (kk0 + ks) * 4 + lhi;
        const float* wp = W + ((size_t)n * 160 + cj) * 8;
        float4 w0 = *(const float4*)wp;
        float4 w1 = *(const float4*)(wp + 4);
        union { short s[8]; bf16x8s v; } bu;
        bu.s[0] = f2bf(w0.x); bu.s[1] = f2bf(w0.y);
        bu.s[2] = f2bf(w0.z); bu.s[3] = f2bf(w0.w);
        bu.s[4] = f2bf(w1.x); bu.s[5] = f2bf(w1.y);
        bu.s[6] = f2bf(w1.z); bu.s[7] = f2bf(w1.w);
        const short* ap = capsb + (size_t)n * 8;
        #pragma unroll
        for (int mt = 0; mt < 4; ++mt) {
            int b = mt * 16 + l15;
            bf16x8s afrag = *(const bf16x8s*)(ap + (size_t)b * 8192 * 8);
            acc[mt] = __builtin_amdgcn_mfma_f32_16x16x32_bf16(afrag, bu.v, acc[mt], 0, 0, 0);
        }
    }

    // C[row=b-local=(lhi*4+r)][col=l15] per m-tile -> red[wv][b][cjl]
    #pragma unroll
    for (int mt = 0; mt < 4; ++mt) {
        #pragma unroll
        for (int r = 0; r < 4; ++r) {
            red[wv][mt * 16 + lhi * 4 + r][l15] = acc[mt][r];
        }
    }
    __syncthreads();

    for (int idx = t; idx < 1024; idx += 256) {
        int b = idx >> 4, cjl = idx & 15;
        float sum = red[0][b][cjl] + red[1][b][cjl] + red[2][b][cjl] + red[3][b][cjl];
        partials[(((size_t)kc * 10 + ntile) * 64 + b) * 16 + cjl] = sum;
    }
}

// ---------------- final reduce + squash + norm -------------------------------
__global__ __launch_bounds__(256) void finalize_kernel(
        const float* __restrict__ partials, float* __restrict__ out) {
    __shared__ float s_sh[160];
    int t = threadIdx.x;
    int b = blockIdx.x;
    if (t < 160) {
        int nt = t >> 4, cjl = t & 15;
        float s = 0.0f;
        #pragma unroll 8
        for (int kc = 0; kc < 64; ++kc)
            s += partials[(((size_t)kc * 10 + nt) * 64 + b) * 16 + cjl];
        s_sh[t] = s * (1.0f / 8192.0f);
    }
    __syncthreads();
    if (t < 10) {
        float sq = 0.0f;
        #pragma unroll
        for (int j = 0; j < 16; ++j) {
            float v = s_sh[t * 16 + j];
            sq += v * v;
        }
        float scale = sq / ((1.0f + sq) * sqrtf(sq + 1e-8f));
        out[b * 10 + t] = sqrtf(sq) * scale;
    }
}

extern "C" void kernel_launch(void* const* d_in, const int* in_sizes, int n_in,
                              void* d_out, int out_size, void* d_ws, size_t ws_size,
                              hipStream_t stream) {
    const float* x_hsi = (const float*)d_in[0];   // [64,144,32,32]
    const float* x_sar = (const float*)d_in[1];   // [64,4,32,32]
    const float* wh    = (const float*)d_in[2];   // [32,144,3,3]
    const float* bh    = (const float*)d_in[3];   // [32]
    const float* wsar  = (const float*)d_in[4];   // [32,4,3,3]
    const float* bs    = (const float*)d_in[5];   // [32]
    const float* W     = (const float*)d_in[6];   // [8192,10,16,8]
    float* out = (float*)d_out;                   // [64,10]

    char* ws = (char*)d_ws;
    short* wtb     = (short*)(ws + 0);            // 9*32*160*2 = 92160 B
    float* wt_s    = (float*)(ws + 92672);        // 4*9*32*4 = 4608 B
    short* xb      = (short*)(ws + 102400);       // 64*1024*160*2 = 20971520 B
    short* capsb   = (short*)(ws + 21073920);     // 64*8192*8*2 = 8388608 B
    float* partials = (float*)(ws + 29462528);    // 64*10*64*16*4 = 2621440 B

    prep_w_kernel<<<180, 256, 0, stream>>>(wh, wtb);
    prep_x_kernel<<<2048, 256, 0, stream>>>(x_hsi, xb);
    transpose_w_kernel<<<5, 256, 0, stream>>>(wsar, wt_s, 4);

    conv_mfma_kernel<<<1024, 256, 0, stream>>>(xb, wtb, bh, capsb);
    conv_caps_sar_kernel<<<1024, 256, 0, stream>>>(x_sar, wt_s, bs, capsb, 4096);

    routing_mfma_kernel<<<dim3(64, 10), 256, 0, stream>>>(capsb, W, partials);

    finalize_kernel<<<64, 256, 0, stream>>>(partials, out);
}